// Round 15
// baseline (190.858 us; speedup 1.0000x reference)
//
#include <hip/hip_runtime.h>
#include <math.h>

#define H_ 256
#define W_ 256
#define HW_ 65536
#define BHW_ 131072   // B*H*W, B=2
#define NPC 8388608   // BHW_*64

typedef __attribute__((ext_vector_type(8))) short short8v;   // 8 bf16 (4 VGPRs)
typedef __attribute__((ext_vector_type(4))) float f32x4;

// gelu(x) = 0.5x(1+tanh(t)) == x * sigmoid(2t)
__device__ __forceinline__ float geluf(float x) {
    const float k2 = 2.f * 0.7978845608028654f;
    float t2 = k2 * (x + 0.044715f * x * x * x);
    return x / (1.f + __expf(-t2));
}
__device__ __forceinline__ float siluf(float x) {
    return x / (1.f + __expf(-x));
}
__device__ __forceinline__ unsigned short f2bf(float f) {   // RNE fp32->bf16
    unsigned u = __float_as_uint(f);
    u = (u + 0x7FFF + ((u >> 16) & 1)) >> 16;
    return (unsigned short)u;
}
__device__ __forceinline__ float bf2f(unsigned short s) {
    return __uint_as_float((unsigned)s << 16);
}

__device__ __forceinline__ float wcomb(const float* Woff, const float* Wmask, int c, int j) {
    return j < 72 ? Woff[c * 72 + j] : (j < 108 ? Wmask[c * 36 + (j - 72)] : 0.f);
}

// ---------- mega: poisson(0..511) | adw(512..2559) | conv1(2560..3071) | prep(3072) ----------
// LDS capped at 12.8 KB (poisson dv in regs, adw 'at' in bf16) -> 8 blocks/CU.
__global__ __launch_bounds__(256) void k_mega(const float* __restrict__ x,
        float* __restrict__ gray,
        const float* __restrict__ Wa, const float* __restrict__ ba,
        const float* __restrict__ dwW, float* __restrict__ a2,
        const float* __restrict__ rw1, const float* __restrict__ rb1,
        float* __restrict__ h1,
        const float* __restrict__ Woff, const float* __restrict__ boff,
        const float* __restrict__ Wmask, const float* __restrict__ bmask,
        const float* __restrict__ Wout, const float* __restrict__ rw2,
        const float* __restrict__ rw3,
        unsigned short* __restrict__ WBpack, unsigned short* __restrict__ WOpack,
        unsigned short* __restrict__ WB2,
        float* __restrict__ bcomb, float* __restrict__ wT3) {
    __shared__ float smem[3200];   // 12.8 KB
    int bid = blockIdx.x;
    int tid = threadIdx.x;

    if (bid < 512) {
        // ---- Poisson: div(regs) + 20 trapezoidal Jacobi iters; 16x16 tile, halo 20 ----
        float* u = smem;            // 56*57 = 3192 floats
        int b = bid >> 8, t = bid & 255;
        int qy = t >> 4, qx = t & 15;
        int y0i = qy << 4, x0i = qx << 4;
        int ys = max(y0i - 20, 0), ye = min(y0i + 35, 255);
        int xs = max(x0i - 20, 0), xe = min(x0i + 35, 255);
        int Ht = ye - ys + 1, Wt = xe - xs + 1;   // <= 56
        int ty = tid >> 5, tx = tid & 31;   // 8 x 32
        const float* x5 = x + ((size_t)(b * 9 + 5) << 16);
        const float* x6 = x + ((size_t)(b * 9 + 6) << 16);

        float dvr[7][2];   // divergence for this thread's 14 positions
        #pragma unroll
        for (int i = 0; i < 7; ++i) {
            int yy = ty + i * 8;
            #pragma unroll
            for (int j = 0; j < 2; ++j) {
                int xx = tx + j * 32;
                if (yy < Ht && xx < Wt) {
                    int gy = ys + yy, gx = xs + xx;
                    int i00 = (gy << 8) + gx;
                    float v5 = x5[i00], v6 = x6[i00];
                    float d = -0.5f * (v5 + v6) + 0.5f * (v5 - v6);
                    if (gx > 0) d += 0.5f * (x5[i00 - 1] + x6[i00 - 1]);
                    if (gy > 0) d -= 0.5f * (x5[i00 - 256] - x6[i00 - 256]);
                    dvr[i][j] = d;
                    u[yy * 57 + xx] = 0.f;
                }
            }
        }
        __syncthreads();

        float nv[7][2];
        for (int it = 0; it < 20; ++it) {
            int r = 19 - it;
            int by0 = max(y0i - r, 0), by1 = min(y0i + 15 + r, 255);
            int bx0 = max(x0i - r, 0), bx1 = min(x0i + 15 + r, 255);
            #pragma unroll
            for (int i = 0; i < 7; ++i) {
                int yy = ty + i * 8;
                int gy = ys + yy;
                #pragma unroll
                for (int j = 0; j < 2; ++j) {
                    int xx = tx + j * 32;
                    int gx = xs + xx;
                    if (gy >= by0 && gy <= by1 && gx >= bx0 && gx <= bx1) {
                        int ym = (gy > 0 ? gy - 1 : 0) - ys;
                        int yp = (gy < 255 ? gy + 1 : 255) - ys;
                        int xm = (gx > 0 ? gx - 1 : 0) - xs;
                        int xp = (gx < 255 ? gx + 1 : 255) - xs;
                        nv[i][j] = (u[ym * 57 + xx] + u[yp * 57 + xx] +
                                    u[yy * 57 + xm] + u[yy * 57 + xp] - dvr[i][j]) * 0.25f;
                    }
                }
            }
            __syncthreads();
            #pragma unroll
            for (int i = 0; i < 7; ++i) {
                int yy = ty + i * 8;
                int gy = ys + yy;
                #pragma unroll
                for (int j = 0; j < 2; ++j) {
                    int xx = tx + j * 32;
                    int gx = xs + xx;
                    if (gy >= by0 && gy <= by1 && gx >= bx0 && gx <= bx1)
                        u[yy * 57 + xx] = nv[i][j];
                }
            }
            __syncthreads();
        }

        int oy = tid >> 4, ox = tid & 15;
        int gy = y0i + oy, gx = x0i + ox;
        gray[((size_t)b << 16) + (gy << 8) + gx] = u[(gy - ys) * 57 + (gx - xs)];

    } else if (bid < 2560) {
        // ---- fused aproj + depthwise + gelu: tile 8x8, halo 1; 'at' in bf16 ----
        unsigned short (*at)[64] = (unsigned short (*)[64])smem;   // 100*64 ush = 12.8 KB
        int abid = bid - 512;
        int b = abid >> 10, tb = abid & 1023;
        int ty0 = (tb >> 5) << 3, tx0 = (tb & 31) << 3;
        const float* g0p = x + ((size_t)(b * 9 + 7) << 16);
        const float* g1p = x + ((size_t)(b * 9 + 8) << 16);
        const float* g2p = x + ((size_t)(b * 9 + 5) << 16);
        const float* g3p = x + ((size_t)(b * 9 + 6) << 16);
        int c = tid & 63;
        float w0 = Wa[c], w1 = Wa[64 + c], w2 = Wa[128 + c], w3 = Wa[192 + c];
        float bb = ba[c];
        #pragma unroll
        for (int rep = 0; rep < 25; ++rep) {
            int pos = rep * 4 + (tid >> 6);
            int py = pos / 10, pxx = pos - py * 10;
            int gy = ty0 - 1 + py, gx = tx0 - 1 + pxx;
            float v = 0.f;
            if ((unsigned)gy < 256u && (unsigned)gx < 256u) {
                int ii = (gy << 8) + gx;
                float tv = bb + g0p[ii] * w0 + g1p[ii] * w1 + g2p[ii] * w2 + g3p[ii] * w3;
                v = geluf(tv);
            }
            at[pos][c] = f2bf(v);
        }
        __syncthreads();
        float dwr[9];
        #pragma unroll
        for (int k = 0; k < 9; ++k) dwr[k] = dwW[k * 64 + c];
        int pgrp = tid >> 6;
        #pragma unroll
        for (int i = 0; i < 16; ++i) {
            int pl = pgrp * 16 + i;
            int pyl = pl >> 3, pxl = pl & 7;
            float s = 0.f;
            #pragma unroll
            for (int kh = 0; kh < 3; ++kh)
                #pragma unroll
                for (int kw = 0; kw < 3; ++kw)
                    s += bf2f(at[(pyl + kh) * 10 + (pxl + kw)][c]) * dwr[kh * 3 + kw];
            int gy = ty0 + pyl, gx = tx0 + pxl;
            a2[(((size_t)(b << 16) + (gy << 8) + gx) << 6) + c] = geluf(s);
        }

    } else if (bid < 3072) {
        // ---- conv1: 7 -> 32, silu; LDS-transposed weights ----
        float* wsT = smem;   // 2016 floats
        for (int j = tid; j < 2016; j += 256) {
            int wb = j >> 5, o = j & 31;
            wsT[j] = rw1[o * 63 + wb];
        }
        __syncthreads();
        int cbid = bid - 2560;
        int wid = (cbid * 256 + tid) >> 6;
        int lane = tid & 63;
        int pix0 = wid << 6;
        int b = pix0 >> 16, hw0 = pix0 & 65535;
        int h = hw0 >> 8, w0 = hw0 & 255;
        float acc[32];
        #pragma unroll
        for (int o = 0; o < 32; ++o) acc[o] = rb1[o];
        const float* inb = x + ((size_t)(b * 9) << 16);
        #pragma unroll
        for (int kh = 0; kh < 3; ++kh) {
            int y = h + kh - 1;
            if ((unsigned)y >= 256u) continue;
            #pragma unroll
            for (int kw = 0; kw < 3; ++kw) {
                int xx = w0 + lane + kw - 1;
                bool valid = (unsigned)xx < 256u;
                int xc = min(max(xx, 0), 255);
                const float* p0 = inb + (y << 8) + xc;
                #pragma unroll
                for (int ci = 0; ci < 7; ++ci) {
                    float v = p0[ci << 16];
                    v = valid ? v : 0.f;
                    const float* wr = &wsT[(ci * 9 + kh * 3 + kw) * 32];
                    #pragma unroll
                    for (int o = 0; o < 32; ++o) acc[o] = fmaf(v, wr[o], acc[o]);
                }
            }
        }
        #pragma unroll
        for (int o = 0; o < 32; ++o)
            h1[((size_t)(b * 32 + o) << 16) + hw0 + lane] = siluf(acc[o]);

    } else {
        // ---- prep: bf16 MFMA weight packs + bcomb + conv3 weight transpose ----
        for (int idx = tid; idx < 8192; idx += 256) {
            int j = idx & 7, l = (idx >> 3) & 63, s = (idx >> 9) & 1, t = idx >> 10;
            int c = s * 32 + ((l >> 4) << 3) + j;
            int col = t * 16 + (l & 15);
            WBpack[idx] = f2bf(wcomb(Woff, Wmask, c, col));
        }
        for (int idx = tid; idx < 4096; idx += 256) {
            int j = idx & 7, l = (idx >> 3) & 63, s = (idx >> 9) & 1, t = (idx >> 10) & 3;
            int c = s * 32 + ((l >> 4) << 3) + j;
            int col = t * 16 + (l & 15);
            WOpack[idx] = f2bf(Wout[c * 64 + col]);
        }
        for (int idx = tid; idx < 9216; idx += 256) {
            int j = idx & 7, l = (idx >> 3) & 63, t = (idx >> 9) & 1, kk = idx >> 10;
            int o = t * 16 + (l & 15);
            int ci = ((l >> 4) << 3) + j;
            WB2[idx] = f2bf(rw2[o * 288 + ci * 9 + kk]);
        }
        if (tid < 128) bcomb[tid] = tid < 72 ? boff[tid] : (tid < 108 ? bmask[tid - 72] : 0.f);
        for (int j = tid; j < 288 * 3; j += 256) {
            int jj = j / 3, o = j - jj * 3;
            wT3[j] = rw3[o * 288 + jj];
        }
    }
}

// ---------- conv2 via MFMA: 16 px/wave, 9 windows x 2 mfma_16x16x32_bf16 ----------
__global__ __launch_bounds__(256) void k_conv2m(const float* __restrict__ h1,
        const unsigned short* __restrict__ WB2, const float* __restrict__ bias,
        float* __restrict__ h2) {
    int tid = threadIdx.x;
    int wave = tid >> 6, lane = tid & 63;
    int pix0 = (blockIdx.x << 6) + (wave << 4);   // 16-px strip, single row
    int b = pix0 >> 16, hw0 = pix0 & 65535;
    int h = hw0 >> 8, w0 = hw0 & 255;
    int px = lane & 15, kg = lane >> 4;
    const float* inb = h1 + ((size_t)(b * 32) << 16);

    short8v af[9][2];
    #pragma unroll
    for (int kk = 0; kk < 9; ++kk) {
        af[kk][0] = *(const short8v*)&WB2[kk * 1024 + (lane << 3)];
        af[kk][1] = *(const short8v*)&WB2[kk * 1024 + 512 + (lane << 3)];
    }

    f32x4 acc0 = {0.f, 0.f, 0.f, 0.f};
    f32x4 acc1 = {0.f, 0.f, 0.f, 0.f};
    #pragma unroll
    for (int kh = 0; kh < 3; ++kh) {
        int y = h + kh - 1;
        if ((unsigned)y >= 256u) continue;     // wave-uniform zero-pad skip
        #pragma unroll
        for (int kw = 0; kw < 3; ++kw) {
            int xx = w0 + px + kw - 1;
            bool valid = (unsigned)xx < 256u;
            int xc = min(max(xx, 0), 255);
            const float* p0 = inb + (y << 8) + xc + ((size_t)kg << 19);  // kg*8 channels
            short8v bfv;
            #pragma unroll
            for (int j = 0; j < 8; ++j) {
                float v = p0[(size_t)j << 16];
                v = valid ? v : 0.f;
                bfv[j] = (short)f2bf(v);
            }
            int kk = kh * 3 + kw;
            acc0 = __builtin_amdgcn_mfma_f32_16x16x32_bf16(af[kk][0], bfv, acc0, 0, 0, 0);
            acc1 = __builtin_amdgcn_mfma_f32_16x16x32_bf16(af[kk][1], bfv, acc1, 0, 0, 0);
        }
    }
    size_t outb = ((size_t)(b * 32) << 16) + (size_t)(hw0 + px);
    #pragma unroll
    for (int r = 0; r < 4; ++r) {
        int o = (kg << 2) + r;
        h2[outb + ((size_t)o << 16)] = siluf(acc0[r] + bias[o]);
        h2[outb + ((size_t)(o + 16) << 16)] = siluf(acc1[r] + bias[o + 16]);
    }
}

// ---------- fused conv3 + xproj: 1 thread/pixel, LDS restage, coalesced xg ----------
__global__ __launch_bounds__(256) void k_c3x(const float* __restrict__ x,
        const float* __restrict__ gray, const float* __restrict__ h2,
        const float* __restrict__ wT3, const float* __restrict__ rb3,
        const float* __restrict__ Wi, const float* __restrict__ bi,
        float* __restrict__ xg) {
    __shared__ float st[7][256];
    int tid = threadIdx.x;
    int pixbase = blockIdx.x << 8;
    int pix = pixbase + tid;
    int b = pix >> 16, hw = pix & 65535;
    int h = hw >> 8, w = hw & 255;

    float a0 = rb3[0], a1 = rb3[1], a2v = rb3[2];
    const float* inb = h2 + ((size_t)(b * 32) << 16);
    #pragma unroll
    for (int kh = 0; kh < 3; ++kh) {
        int y = h + kh - 1;
        if ((unsigned)y >= 256u) continue;
        #pragma unroll
        for (int kw = 0; kw < 3; ++kw) {
            int xx = w + kw - 1;
            bool valid = (unsigned)xx < 256u;
            int xc = min(max(xx, 0), 255);
            const float* p0 = inb + (y << 8) + xc;
            #pragma unroll 8
            for (int ci = 0; ci < 32; ++ci) {
                float v = p0[ci << 16];
                v = valid ? v : 0.f;
                const float* wr = wT3 + (ci * 9 + kh * 3 + kw) * 3;
                a0 = fmaf(v, wr[0], a0);
                a1 = fmaf(v, wr[1], a1);
                a2v = fmaf(v, wr[2], a2v);
            }
        }
    }
    st[0][tid] = x[((size_t)(b * 9 + 0) << 16) + hw];
    st[1][tid] = x[((size_t)(b * 9 + 1) << 16) + hw];
    st[2][tid] = x[((size_t)(b * 9 + 2) << 16) + hw];
    st[3][tid] = gray[pix];
    st[4][tid] = a0;
    st[5][tid] = a1;
    st[6][tid] = a2v;
    __syncthreads();

    int c = tid & 63, sub = tid >> 6;
    float w0 = Wi[c], w1 = Wi[64 + c], w2 = Wi[128 + c], w3 = Wi[192 + c];
    float w4 = Wi[256 + c], w5 = Wi[320 + c], w6 = Wi[384 + c];
    float bb = bi[c];
    #pragma unroll 4
    for (int rep = 0; rep < 64; ++rep) {
        int pl = rep * 4 + sub;
        float v = bb + st[0][pl] * w0 + st[1][pl] * w1 + st[2][pl] * w2
                + st[3][pl] * w3 + st[4][pl] * w4 + st[5][pl] * w5 + st[6][pl] * w6;
        xg[(((size_t)(pixbase + pl)) << 6) + c] = v;
    }
}

// ---------- DCNv3 core v7: MFMA projections + float2 gather ----------
__global__ __launch_bounds__(256, 4) void k_dcn(
        const float* __restrict__ a2, const float* __restrict__ xg,
        const unsigned short* __restrict__ WBpack,
        const unsigned short* __restrict__ WOpack,
        const float* __restrict__ bcomb, const float* __restrict__ bout,
        float* __restrict__ out) {
    __shared__ __attribute__((aligned(16))) unsigned short a2bf[16][72];  // bf16, padded
    __shared__ __attribute__((aligned(16))) unsigned short accbf[16][72];
    __shared__ __attribute__((aligned(16))) float offs[16][72];
    __shared__ float pms[16][36];
    __shared__ float invs[16][4];
    __shared__ __attribute__((aligned(16))) float taps[16][36][8]; // then outs[16][65]
    float (*outs)[65] = (float (*)[65])&taps[0][0][0];

    int tid = threadIdx.x;
    int wave = tid >> 6, lane = tid & 63;
    int pixbase = blockIdx.x << 4;
    int b = pixbase >> 16, hw0 = pixbase & 65535;
    int h = hw0 >> 8, w0 = hw0 & 255;
    int pw = wave << 2;

    #pragma unroll
    for (int p = 0; p < 4; ++p)
        a2bf[pw + p][lane] = f2bf(a2[((size_t)(pixbase + pw + p) << 6) + lane]);
    __syncthreads();

    // B: off(72)+mask(36) projection via MFMA. Wave w covers cols 32w..32w+31.
    {
        const unsigned short* arow = &a2bf[lane & 15][(lane >> 4) << 3];
        short8v af0 = *(const short8v*)arow;
        short8v af1 = *(const short8v*)(arow + 32);
        #pragma unroll
        for (int t2 = 0; t2 < 2; ++t2) {
            int t = 2 * wave + t2;
            int col = t * 16 + (lane & 15);
            float bc = bcomb[col];
            f32x4 acc = {bc, bc, bc, bc};
            short8v b0 = *(const short8v*)&WBpack[((t * 2 + 0) * 64 + lane) << 3];
            short8v b1 = *(const short8v*)&WBpack[((t * 2 + 1) * 64 + lane) << 3];
            acc = __builtin_amdgcn_mfma_f32_16x16x32_bf16(af0, b0, acc, 0, 0, 0);
            acc = __builtin_amdgcn_mfma_f32_16x16x32_bf16(af1, b1, acc, 0, 0, 0);
            int pxb = (lane >> 4) << 2;
            #pragma unroll
            for (int r = 0; r < 4; ++r) {
                float v = acc[r];
                int px = pxb + r;
                if (col < 72) offs[px][col] = v;
                else if (col < 108) pms[px][col - 72] = __expf(v);   // shift-free softmax
            }
        }
    }
    __syncthreads();

    if (lane < 16) {
        int p = lane >> 2, g = lane & 3;
        const float* m = &pms[pw + p][g * 9];
        float s = m[0]+m[1]+m[2]+m[3]+m[4]+m[5]+m[6]+m[7]+m[8];
        invs[pw + p][g] = 1.f / s;
    }
    #pragma unroll
    for (int rep = 0; rep < 3; ++rep) {
        int idx = rep * 64 + lane;
        if (idx < 144) {
            int p = idx / 36, j = idx - p * 36;
            int px = pw + p;
            int g = j / 9, k = j - g * 9;
            float2 oxy = ((const float2*)&offs[px][0])[j];
            float pm = pms[px][j] * invs[px][g];
            float ly = (float)(h + k / 3 - 1) + oxy.x;
            float lx = (float)(w0 + px + (k % 3) - 1) + oxy.y;
            float y0f = floorf(ly), x0f = floorf(lx);
            float wy = ly - y0f, wx = lx - x0f;
            int iy0 = (int)y0f, ix0 = (int)x0f;
            int base = b << 16;
            float4 t01, t23;
            {
                int yi = iy0, xi = ix0;
                float wgt = (1.f - wy) * (1.f - wx) * pm;
                if (yi < 0 || yi > 255 || xi < 0 || xi > 255) wgt = 0.f;
                int yc = min(max(yi, 0), 255), xc = min(max(xi, 0), 255);
                t01.x = __int_as_float((base + (yc << 8) + xc) << 8); t01.y = wgt;
            }
            {
                int yi = iy0, xi = ix0 + 1;
                float wgt = (1.f - wy) * wx * pm;
                if (yi < 0 || yi > 255 || xi < 0 || xi > 255) wgt = 0.f;
                int yc = min(max(yi, 0), 255), xc = min(max(xi, 0), 255);
                t01.z = __int_as_float((base + (yc << 8) + xc) << 8); t01.w = wgt;
            }
            {
                int yi = iy0 + 1, xi = ix0;
                float wgt = wy * (1.f - wx) * pm;
                if (yi < 0 || yi > 255 || xi < 0 || xi > 255) wgt = 0.f;
                int yc = min(max(yi, 0), 255), xc = min(max(xi, 0), 255);
                t23.x = __int_as_float((base + (yc << 8) + xc) << 8); t23.y = wgt;
            }
            {
                int yi = iy0 + 1, xi = ix0 + 1;
                float wgt = wy * wx * pm;
                if (yi < 0 || yi > 255 || xi < 0 || xi > 255) wgt = 0.f;
                int yc = min(max(yi, 0), 255), xc = min(max(xi, 0), 255);
                t23.z = __int_as_float((base + (yc << 8) + xc) << 8); t23.w = wgt;
            }
            ((float4*)&taps[px][j][0])[0] = t01;
            ((float4*)&taps[px][j][0])[1] = t23;
        }
    }
    // F: float2 gather; lane = px2*32 + cp (cp = channel pair 0..31, g = cp>>3)
    {
        int cp = lane & 31, px2 = lane >> 5;
        int g9 = (cp >> 3) * 9;
        const char* xgb = (const char*)xg;
        unsigned cp8 = (unsigned)(cp << 3);
        #pragma unroll
        for (int pr = 0; pr < 2; ++pr) {
            int px = pw + pr * 2 + px2;
            float ax = 0.f, ay = 0.f;
            const float4* tp4 = (const float4*)&taps[px][g9][0];
            #pragma unroll
            for (int k = 0; k < 9; ++k) {
                float4 d0 = tp4[2 * k], d1 = tp4[2 * k + 1];
                {
                    float2 v = *(const float2*)(xgb + ((unsigned)__float_as_int(d0.x) + cp8));
                    ax = fmaf(d0.y, v.x, ax); ay = fmaf(d0.y, v.y, ay);
                }
                {
                    float2 v = *(const float2*)(xgb + ((unsigned)__float_as_int(d0.z) + cp8));
                    ax = fmaf(d0.w, v.x, ax); ay = fmaf(d0.w, v.y, ay);
                }
                {
                    float2 v = *(const float2*)(xgb + ((unsigned)__float_as_int(d1.x) + cp8));
                    ax = fmaf(d1.y, v.x, ax); ay = fmaf(d1.y, v.y, ay);
                }
                {
                    float2 v = *(const float2*)(xgb + ((unsigned)__float_as_int(d1.z) + cp8));
                    ax = fmaf(d1.w, v.x, ax); ay = fmaf(d1.w, v.y, ay);
                }
            }
            // G: packed bf16 pair store (channels 2cp, 2cp+1)
            unsigned packed = (unsigned)f2bf(ax) | ((unsigned)f2bf(ay) << 16);
            *(unsigned*)&accbf[px][cp << 1] = packed;
        }
    }
    __syncthreads();   // taps dead in all waves; accbf complete

    // H: out projection via MFMA. Wave w covers cols 16w..16w+15.
    {
        const unsigned short* arow = &accbf[lane & 15][(lane >> 4) << 3];
        short8v hf0 = *(const short8v*)arow;
        short8v hf1 = *(const short8v*)(arow + 32);
        int t = wave;
        int col = t * 16 + (lane & 15);
        float bo = bout[col];
        f32x4 acc = {bo, bo, bo, bo};
        short8v w0v = *(const short8v*)&WOpack[((t * 2 + 0) * 64 + lane) << 3];
        short8v w1v = *(const short8v*)&WOpack[((t * 2 + 1) * 64 + lane) << 3];
        acc = __builtin_amdgcn_mfma_f32_16x16x32_bf16(hf0, w0v, acc, 0, 0, 0);
        acc = __builtin_amdgcn_mfma_f32_16x16x32_bf16(hf1, w1v, acc, 0, 0, 0);
        int pxb = (lane >> 4) << 2;
        #pragma unroll
        for (int r = 0; r < 4; ++r)
            outs[pxb + r][col] = acc[r];
    }
    __syncthreads();

    int cq = tid >> 4, px = tid & 15;
    size_t rowb = ((size_t)(b * 64) << 16) + hw0 + px;
    #pragma unroll
    for (int rep = 0; rep < 4; ++rep) {
        int c = cq + rep * 16;
        out[rowb + ((size_t)c << 16)] = outs[px][c];
    }
}

extern "C" void kernel_launch(void* const* d_in, const int* in_sizes, int n_in,
                              void* d_out, int out_size, void* d_ws, size_t ws_size,
                              hipStream_t stream) {
    const float* x      = (const float*)d_in[0];
    const float* rw1    = (const float*)d_in[1];
    const float* rb1    = (const float*)d_in[2];
    const float* rw2    = (const float*)d_in[3];
    const float* rb2    = (const float*)d_in[4];
    const float* rw3    = (const float*)d_in[5];
    const float* rb3    = (const float*)d_in[6];
    const float* W_in   = (const float*)d_in[7];
    const float* b_in   = (const float*)d_in[8];
    const float* W_aop  = (const float*)d_in[9];
    const float* b_aop  = (const float*)d_in[10];
    const float* dw     = (const float*)d_in[11];
    const float* W_off  = (const float*)d_in[12];
    const float* b_off  = (const float*)d_in[13];
    const float* W_mask = (const float*)d_in[14];
    const float* b_mask = (const float*)d_in[15];
    const float* W_out  = (const float*)d_in[16];
    const float* b_out  = (const float*)d_in[17];
    float* out = (float*)d_out;

    // Large arrays FIRST: every offset multiple of 131072 floats ->
    // a2/xg pixel rows (256 B) stay 256B-aligned (R4/R5 lesson: 4x FETCH if broken).
    float* ws = (float*)d_ws;
    float* gray  = ws;                        // 131072
    float* h1    = gray + BHW_;               // 4194304
    float* h2    = h1 + (size_t)BHW_ * 32;    // 4194304
    float* a2    = h2 + (size_t)BHW_ * 32;    // 8388608  (256B-aligned)
    float* xg    = a2 + (size_t)NPC;          // 8388608  (256B-aligned)
    float* bcomb = xg + (size_t)NPC;          // 128
    float* wT3   = bcomb + 128;               // 864; 128+864=992 floats -> 16B-aligned next
    unsigned short* WBpack = (unsigned short*)(wT3 + 864);   // 8192 bf16 = 16 KB
    unsigned short* WOpack = WBpack + 8192;                  // 4096 bf16 = 8 KB
    unsigned short* WB2    = WOpack + 4096;                  // 9216 bf16 = 18 KB

    dim3 blk(256);

    k_mega<<<dim3(3073), blk, 0, stream>>>(x, gray, W_aop, b_aop, dw, a2,
                                           rw1, rb1, h1,
                                           W_off, b_off, W_mask, b_mask, W_out,
                                           rw2, rw3,
                                           WBpack, WOpack, WB2, bcomb, wT3);
    k_conv2m<<<dim3(BHW_ / 64), blk, 0, stream>>>(h1, WB2, rb2, h2);
    k_c3x<<<dim3(BHW_ / 256), blk, 0, stream>>>(x, gray, h2, wT3, rb3,
                                                W_in, b_in, xg);
    k_dcn<<<dim3(BHW_ / 16), blk, 0, stream>>>(a2, xg, WBpack, WOpack,
                                               bcomb, b_out, out);
}

// Round 16
// 161.333 us; speedup vs baseline: 1.1830x; 1.1830x over previous
//
#include <hip/hip_runtime.h>
#include <math.h>

#define H_ 256
#define W_ 256
#define HW_ 65536
#define BHW_ 131072   // B*H*W, B=2
#define NPC 8388608   // BHW_*64

typedef __attribute__((ext_vector_type(8))) short short8v;   // 8 bf16 (4 VGPRs)
typedef __attribute__((ext_vector_type(4))) float f32x4;

// gelu(x) = 0.5x(1+tanh(t)) == x * sigmoid(2t)
__device__ __forceinline__ float geluf(float x) {
    const float k2 = 2.f * 0.7978845608028654f;
    float t2 = k2 * (x + 0.044715f * x * x * x);
    return x / (1.f + __expf(-t2));
}
__device__ __forceinline__ float siluf(float x) {
    return x / (1.f + __expf(-x));
}
__device__ __forceinline__ unsigned short f2bf(float f) {   // RNE fp32->bf16
    unsigned u = __float_as_uint(f);
    u = (u + 0x7FFF + ((u >> 16) & 1)) >> 16;
    return (unsigned short)u;
}
__device__ __forceinline__ float bf2f(unsigned short s) {
    return __uint_as_float((unsigned)s << 16);
}

__device__ __forceinline__ float wcomb(const float* Woff, const float* Wmask, int c, int j) {
    return j < 72 ? Woff[c * 72 + j] : (j < 108 ? Wmask[c * 36 + (j - 72)] : 0.f);
}

// ---------- mega: poisson(0..511) | adw(512..2559) | conv1(2560..3071) | prep(3072) ----------
__global__ __launch_bounds__(256) void k_mega(const float* __restrict__ x,
        float* __restrict__ gray,
        const float* __restrict__ Wa, const float* __restrict__ ba,
        const float* __restrict__ dwW, float* __restrict__ a2,
        const float* __restrict__ rw1, const float* __restrict__ rb1,
        float* __restrict__ h1,
        const float* __restrict__ Woff, const float* __restrict__ boff,
        const float* __restrict__ Wmask, const float* __restrict__ bmask,
        const float* __restrict__ Wout, const float* __restrict__ rw2,
        const float* __restrict__ rw3,
        unsigned short* __restrict__ WBpack, unsigned short* __restrict__ WOpack,
        unsigned short* __restrict__ WB2,
        float* __restrict__ bcomb, float* __restrict__ wT3) {
    __shared__ float smem[3200];   // 12.8 KB
    int bid = blockIdx.x;
    int tid = threadIdx.x;

    if (bid < 512) {
        // ---- Poisson: div(regs) + 20 trapezoidal Jacobi iters; 16x16 tile, halo 20 ----
        float* u = smem;            // 56*57 = 3192 floats
        int b = bid >> 8, t = bid & 255;
        int qy = t >> 4, qx = t & 15;
        int y0i = qy << 4, x0i = qx << 4;
        int ys = max(y0i - 20, 0), ye = min(y0i + 35, 255);
        int xs = max(x0i - 20, 0), xe = min(x0i + 35, 255);
        int Ht = ye - ys + 1, Wt = xe - xs + 1;   // <= 56
        int ty = tid >> 5, tx = tid & 31;   // 8 x 32
        const float* x5 = x + ((size_t)(b * 9 + 5) << 16);
        const float* x6 = x + ((size_t)(b * 9 + 6) << 16);

        float dvr[7][2];
        #pragma unroll
        for (int i = 0; i < 7; ++i) {
            int yy = ty + i * 8;
            #pragma unroll
            for (int j = 0; j < 2; ++j) {
                int xx = tx + j * 32;
                if (yy < Ht && xx < Wt) {
                    int gy = ys + yy, gx = xs + xx;
                    int i00 = (gy << 8) + gx;
                    float v5 = x5[i00], v6 = x6[i00];
                    float d = -0.5f * (v5 + v6) + 0.5f * (v5 - v6);
                    if (gx > 0) d += 0.5f * (x5[i00 - 1] + x6[i00 - 1]);
                    if (gy > 0) d -= 0.5f * (x5[i00 - 256] - x6[i00 - 256]);
                    dvr[i][j] = d;
                    u[yy * 57 + xx] = 0.f;
                }
            }
        }
        __syncthreads();

        float nv[7][2];
        for (int it = 0; it < 20; ++it) {
            int r = 19 - it;
            int by0 = max(y0i - r, 0), by1 = min(y0i + 15 + r, 255);
            int bx0 = max(x0i - r, 0), bx1 = min(x0i + 15 + r, 255);
            #pragma unroll
            for (int i = 0; i < 7; ++i) {
                int yy = ty + i * 8;
                int gy = ys + yy;
                #pragma unroll
                for (int j = 0; j < 2; ++j) {
                    int xx = tx + j * 32;
                    int gx = xs + xx;
                    if (gy >= by0 && gy <= by1 && gx >= bx0 && gx <= bx1) {
                        int ym = (gy > 0 ? gy - 1 : 0) - ys;
                        int yp = (gy < 255 ? gy + 1 : 255) - ys;
                        int xm = (gx > 0 ? gx - 1 : 0) - xs;
                        int xp = (gx < 255 ? gx + 1 : 255) - xs;
                        nv[i][j] = (u[ym * 57 + xx] + u[yp * 57 + xx] +
                                    u[yy * 57 + xm] + u[yy * 57 + xp] - dvr[i][j]) * 0.25f;
                    }
                }
            }
            __syncthreads();
            #pragma unroll
            for (int i = 0; i < 7; ++i) {
                int yy = ty + i * 8;
                int gy = ys + yy;
                #pragma unroll
                for (int j = 0; j < 2; ++j) {
                    int xx = tx + j * 32;
                    int gx = xs + xx;
                    if (gy >= by0 && gy <= by1 && gx >= bx0 && gx <= bx1)
                        u[yy * 57 + xx] = nv[i][j];
                }
            }
            __syncthreads();
        }

        int oy = tid >> 4, ox = tid & 15;
        int gy = y0i + oy, gx = x0i + ox;
        gray[((size_t)b << 16) + (gy << 8) + gx] = u[(gy - ys) * 57 + (gx - xs)];

    } else if (bid < 2560) {
        // ---- fused aproj + depthwise + gelu: tile 8x8, halo 1; 'at' in bf16 ----
        unsigned short (*at)[64] = (unsigned short (*)[64])smem;   // 12.8 KB
        int abid = bid - 512;
        int b = abid >> 10, tb = abid & 1023;
        int ty0 = (tb >> 5) << 3, tx0 = (tb & 31) << 3;
        const float* g0p = x + ((size_t)(b * 9 + 7) << 16);
        const float* g1p = x + ((size_t)(b * 9 + 8) << 16);
        const float* g2p = x + ((size_t)(b * 9 + 5) << 16);
        const float* g3p = x + ((size_t)(b * 9 + 6) << 16);
        int c = tid & 63;
        float w0 = Wa[c], w1 = Wa[64 + c], w2 = Wa[128 + c], w3 = Wa[192 + c];
        float bb = ba[c];
        #pragma unroll
        for (int rep = 0; rep < 25; ++rep) {
            int pos = rep * 4 + (tid >> 6);
            int py = pos / 10, pxx = pos - py * 10;
            int gy = ty0 - 1 + py, gx = tx0 - 1 + pxx;
            float v = 0.f;
            if ((unsigned)gy < 256u && (unsigned)gx < 256u) {
                int ii = (gy << 8) + gx;
                float tv = bb + g0p[ii] * w0 + g1p[ii] * w1 + g2p[ii] * w2 + g3p[ii] * w3;
                v = geluf(tv);
            }
            at[pos][c] = f2bf(v);
        }
        __syncthreads();
        float dwr[9];
        #pragma unroll
        for (int k = 0; k < 9; ++k) dwr[k] = dwW[k * 64 + c];
        int pgrp = tid >> 6;
        #pragma unroll
        for (int i = 0; i < 16; ++i) {
            int pl = pgrp * 16 + i;
            int pyl = pl >> 3, pxl = pl & 7;
            float s = 0.f;
            #pragma unroll
            for (int kh = 0; kh < 3; ++kh)
                #pragma unroll
                for (int kw = 0; kw < 3; ++kw)
                    s += bf2f(at[(pyl + kh) * 10 + (pxl + kw)][c]) * dwr[kh * 3 + kw];
            int gy = ty0 + pyl, gx = tx0 + pxl;
            a2[(((size_t)(b << 16) + (gy << 8) + gx) << 6) + c] = geluf(s);
        }

    } else if (bid < 3072) {
        // ---- conv1: 7 -> 32, silu; LDS-transposed weights ----
        float* wsT = smem;   // 2016 floats
        for (int j = tid; j < 2016; j += 256) {
            int wb = j >> 5, o = j & 31;
            wsT[j] = rw1[o * 63 + wb];
        }
        __syncthreads();
        int cbid = bid - 2560;
        int wid = (cbid * 256 + tid) >> 6;
        int lane = tid & 63;
        int pix0 = wid << 6;
        int b = pix0 >> 16, hw0 = pix0 & 65535;
        int h = hw0 >> 8, w0 = hw0 & 255;
        float acc[32];
        #pragma unroll
        for (int o = 0; o < 32; ++o) acc[o] = rb1[o];
        const float* inb = x + ((size_t)(b * 9) << 16);
        #pragma unroll
        for (int kh = 0; kh < 3; ++kh) {
            int y = h + kh - 1;
            if ((unsigned)y >= 256u) continue;
            #pragma unroll
            for (int kw = 0; kw < 3; ++kw) {
                int xx = w0 + lane + kw - 1;
                bool valid = (unsigned)xx < 256u;
                int xc = min(max(xx, 0), 255);
                const float* p0 = inb + (y << 8) + xc;
                #pragma unroll
                for (int ci = 0; ci < 7; ++ci) {
                    float v = p0[ci << 16];
                    v = valid ? v : 0.f;
                    const float* wr = &wsT[(ci * 9 + kh * 3 + kw) * 32];
                    #pragma unroll
                    for (int o = 0; o < 32; ++o) acc[o] = fmaf(v, wr[o], acc[o]);
                }
            }
        }
        #pragma unroll
        for (int o = 0; o < 32; ++o)
            h1[((size_t)(b * 32 + o) << 16) + hw0 + lane] = siluf(acc[o]);

    } else {
        // ---- prep: bf16 MFMA weight packs + bcomb + conv3 weight transpose ----
        for (int idx = tid; idx < 8192; idx += 256) {
            int j = idx & 7, l = (idx >> 3) & 63, s = (idx >> 9) & 1, t = idx >> 10;
            int c = s * 32 + ((l >> 4) << 3) + j;
            int col = t * 16 + (l & 15);
            WBpack[idx] = f2bf(wcomb(Woff, Wmask, c, col));
        }
        for (int idx = tid; idx < 4096; idx += 256) {
            int j = idx & 7, l = (idx >> 3) & 63, s = (idx >> 9) & 1, t = (idx >> 10) & 3;
            int c = s * 32 + ((l >> 4) << 3) + j;
            int col = t * 16 + (l & 15);
            WOpack[idx] = f2bf(Wout[c * 64 + col]);
        }
        for (int idx = tid; idx < 9216; idx += 256) {
            int j = idx & 7, l = (idx >> 3) & 63, t = (idx >> 9) & 1, kk = idx >> 10;
            int o = t * 16 + (l & 15);
            int ci = ((l >> 4) << 3) + j;
            WB2[idx] = f2bf(rw2[o * 288 + ci * 9 + kk]);
        }
        if (tid < 128) bcomb[tid] = tid < 72 ? boff[tid] : (tid < 108 ? bmask[tid - 72] : 0.f);
        for (int j = tid; j < 288 * 3; j += 256) {
            int jj = j / 3, o = j - jj * 3;
            wT3[j] = rw3[o * 288 + jj];
        }
    }
}

// ---------- conv2 via MFMA: 16 px/wave, 9 windows x 2 mfma_16x16x32_bf16 ----------
__global__ __launch_bounds__(256) void k_conv2m(const float* __restrict__ h1,
        const unsigned short* __restrict__ WB2, const float* __restrict__ bias,
        float* __restrict__ h2) {
    int tid = threadIdx.x;
    int wave = tid >> 6, lane = tid & 63;
    int pix0 = (blockIdx.x << 6) + (wave << 4);   // 16-px strip, single row
    int b = pix0 >> 16, hw0 = pix0 & 65535;
    int h = hw0 >> 8, w0 = hw0 & 255;
    int px = lane & 15, kg = lane >> 4;
    const float* inb = h1 + ((size_t)(b * 32) << 16);

    short8v af[9][2];
    #pragma unroll
    for (int kk = 0; kk < 9; ++kk) {
        af[kk][0] = *(const short8v*)&WB2[kk * 1024 + (lane << 3)];
        af[kk][1] = *(const short8v*)&WB2[kk * 1024 + 512 + (lane << 3)];
    }

    f32x4 acc0 = {0.f, 0.f, 0.f, 0.f};
    f32x4 acc1 = {0.f, 0.f, 0.f, 0.f};
    #pragma unroll
    for (int kh = 0; kh < 3; ++kh) {
        int y = h + kh - 1;
        if ((unsigned)y >= 256u) continue;     // wave-uniform zero-pad skip
        #pragma unroll
        for (int kw = 0; kw < 3; ++kw) {
            int xx = w0 + px + kw - 1;
            bool valid = (unsigned)xx < 256u;
            int xc = min(max(xx, 0), 255);
            const float* p0 = inb + (y << 8) + xc + ((size_t)kg << 19);  // kg*8 channels
            short8v bfv;
            #pragma unroll
            for (int j = 0; j < 8; ++j) {
                float v = p0[(size_t)j << 16];
                v = valid ? v : 0.f;
                bfv[j] = (short)f2bf(v);
            }
            int kk = kh * 3 + kw;
            acc0 = __builtin_amdgcn_mfma_f32_16x16x32_bf16(af[kk][0], bfv, acc0, 0, 0, 0);
            acc1 = __builtin_amdgcn_mfma_f32_16x16x32_bf16(af[kk][1], bfv, acc1, 0, 0, 0);
        }
    }
    size_t outb = ((size_t)(b * 32) << 16) + (size_t)(hw0 + px);
    #pragma unroll
    for (int r = 0; r < 4; ++r) {
        int o = (kg << 2) + r;
        h2[outb + ((size_t)o << 16)] = siluf(acc0[r] + bias[o]);
        h2[outb + ((size_t)(o + 16) << 16)] = siluf(acc1[r] + bias[o + 16]);
    }
}

// ---------- fused conv3 + xproj: 1 thread/pixel, LDS restage; xg stored bf16 ----------
__global__ __launch_bounds__(256) void k_c3x(const float* __restrict__ x,
        const float* __restrict__ gray, const float* __restrict__ h2,
        const float* __restrict__ wT3, const float* __restrict__ rb3,
        const float* __restrict__ Wi, const float* __restrict__ bi,
        unsigned short* __restrict__ xg) {
    __shared__ float st[7][256];
    int tid = threadIdx.x;
    int pixbase = blockIdx.x << 8;
    int pix = pixbase + tid;
    int b = pix >> 16, hw = pix & 65535;
    int h = hw >> 8, w = hw & 255;

    float a0 = rb3[0], a1 = rb3[1], a2v = rb3[2];
    const float* inb = h2 + ((size_t)(b * 32) << 16);
    #pragma unroll
    for (int kh = 0; kh < 3; ++kh) {
        int y = h + kh - 1;
        if ((unsigned)y >= 256u) continue;
        #pragma unroll
        for (int kw = 0; kw < 3; ++kw) {
            int xx = w + kw - 1;
            bool valid = (unsigned)xx < 256u;
            int xc = min(max(xx, 0), 255);
            const float* p0 = inb + (y << 8) + xc;
            #pragma unroll 8
            for (int ci = 0; ci < 32; ++ci) {
                float v = p0[ci << 16];
                v = valid ? v : 0.f;
                const float* wr = wT3 + (ci * 9 + kh * 3 + kw) * 3;
                a0 = fmaf(v, wr[0], a0);
                a1 = fmaf(v, wr[1], a1);
                a2v = fmaf(v, wr[2], a2v);
            }
        }
    }
    st[0][tid] = x[((size_t)(b * 9 + 0) << 16) + hw];
    st[1][tid] = x[((size_t)(b * 9 + 1) << 16) + hw];
    st[2][tid] = x[((size_t)(b * 9 + 2) << 16) + hw];
    st[3][tid] = gray[pix];
    st[4][tid] = a0;
    st[5][tid] = a1;
    st[6][tid] = a2v;
    __syncthreads();

    int c = tid & 63, sub = tid >> 6;
    float w0 = Wi[c], w1 = Wi[64 + c], w2 = Wi[128 + c], w3 = Wi[192 + c];
    float w4 = Wi[256 + c], w5 = Wi[320 + c], w6 = Wi[384 + c];
    float bb = bi[c];
    #pragma unroll 4
    for (int rep = 0; rep < 64; ++rep) {
        int pl = rep * 4 + sub;
        float v = bb + st[0][pl] * w0 + st[1][pl] * w1 + st[2][pl] * w2
                + st[3][pl] * w3 + st[4][pl] * w4 + st[5][pl] * w5 + st[6][pl] * w6;
        xg[(((size_t)(pixbase + pl)) << 6) + c] = f2bf(v);
    }
}

// ---------- DCNv3 core v8: MFMA projections + scalar gather over bf16 xg ----------
__global__ __launch_bounds__(256, 4) void k_dcn(
        const float* __restrict__ a2, const unsigned short* __restrict__ xg,
        const unsigned short* __restrict__ WBpack,
        const unsigned short* __restrict__ WOpack,
        const float* __restrict__ bcomb, const float* __restrict__ bout,
        float* __restrict__ out) {
    __shared__ __attribute__((aligned(16))) unsigned short a2bf[16][72];  // bf16, padded
    __shared__ __attribute__((aligned(16))) unsigned short accbf[16][72];
    __shared__ __attribute__((aligned(16))) float offs[16][72];
    __shared__ float pms[16][36];
    __shared__ float invs[16][4];
    __shared__ __attribute__((aligned(16))) float taps[16][36][8]; // then outs[16][65]
    float (*outs)[65] = (float (*)[65])&taps[0][0][0];

    int tid = threadIdx.x;
    int wave = tid >> 6, lane = tid & 63;
    int pixbase = blockIdx.x << 4;
    int b = pixbase >> 16, hw0 = pixbase & 65535;
    int h = hw0 >> 8, w0 = hw0 & 255;
    int pw = wave << 2;

    #pragma unroll
    for (int p = 0; p < 4; ++p)
        a2bf[pw + p][lane] = f2bf(a2[((size_t)(pixbase + pw + p) << 6) + lane]);
    __syncthreads();

    // B: off(72)+mask(36) projection via MFMA. Wave w covers cols 32w..32w+31.
    {
        const unsigned short* arow = &a2bf[lane & 15][(lane >> 4) << 3];
        short8v af0 = *(const short8v*)arow;
        short8v af1 = *(const short8v*)(arow + 32);
        #pragma unroll
        for (int t2 = 0; t2 < 2; ++t2) {
            int t = 2 * wave + t2;
            int col = t * 16 + (lane & 15);
            float bc = bcomb[col];
            f32x4 acc = {bc, bc, bc, bc};
            short8v b0 = *(const short8v*)&WBpack[((t * 2 + 0) * 64 + lane) << 3];
            short8v b1 = *(const short8v*)&WBpack[((t * 2 + 1) * 64 + lane) << 3];
            acc = __builtin_amdgcn_mfma_f32_16x16x32_bf16(af0, b0, acc, 0, 0, 0);
            acc = __builtin_amdgcn_mfma_f32_16x16x32_bf16(af1, b1, acc, 0, 0, 0);
            int pxb = (lane >> 4) << 2;
            #pragma unroll
            for (int r = 0; r < 4; ++r) {
                float v = acc[r];
                int px = pxb + r;
                if (col < 72) offs[px][col] = v;
                else if (col < 108) pms[px][col - 72] = __expf(v);   // shift-free softmax
            }
        }
    }
    __syncthreads();

    if (lane < 16) {
        int p = lane >> 2, g = lane & 3;
        const float* m = &pms[pw + p][g * 9];
        float s = m[0]+m[1]+m[2]+m[3]+m[4]+m[5]+m[6]+m[7]+m[8];
        invs[pw + p][g] = 1.f / s;
    }
    // E: tap descriptors (BYTE offsets = spatial<<7, bf16 rows), 144 jobs
    #pragma unroll
    for (int rep = 0; rep < 3; ++rep) {
        int idx = rep * 64 + lane;
        if (idx < 144) {
            int p = idx / 36, j = idx - p * 36;
            int px = pw + p;
            int g = j / 9, k = j - g * 9;
            float2 oxy = ((const float2*)&offs[px][0])[j];
            float pm = pms[px][j] * invs[px][g];
            float ly = (float)(h + k / 3 - 1) + oxy.x;
            float lx = (float)(w0 + px + (k % 3) - 1) + oxy.y;
            float y0f = floorf(ly), x0f = floorf(lx);
            float wy = ly - y0f, wx = lx - x0f;
            int iy0 = (int)y0f, ix0 = (int)x0f;
            int base = b << 16;
            float4 t01, t23;
            {
                int yi = iy0, xi = ix0;
                float wgt = (1.f - wy) * (1.f - wx) * pm;
                if (yi < 0 || yi > 255 || xi < 0 || xi > 255) wgt = 0.f;
                int yc = min(max(yi, 0), 255), xc = min(max(xi, 0), 255);
                t01.x = __int_as_float((base + (yc << 8) + xc) << 7); t01.y = wgt;
            }
            {
                int yi = iy0, xi = ix0 + 1;
                float wgt = (1.f - wy) * wx * pm;
                if (yi < 0 || yi > 255 || xi < 0 || xi > 255) wgt = 0.f;
                int yc = min(max(yi, 0), 255), xc = min(max(xi, 0), 255);
                t01.z = __int_as_float((base + (yc << 8) + xc) << 7); t01.w = wgt;
            }
            {
                int yi = iy0 + 1, xi = ix0;
                float wgt = wy * (1.f - wx) * pm;
                if (yi < 0 || yi > 255 || xi < 0 || xi > 255) wgt = 0.f;
                int yc = min(max(yi, 0), 255), xc = min(max(xi, 0), 255);
                t23.x = __int_as_float((base + (yc << 8) + xc) << 7); t23.y = wgt;
            }
            {
                int yi = iy0 + 1, xi = ix0 + 1;
                float wgt = wy * wx * pm;
                if (yi < 0 || yi > 255 || xi < 0 || xi > 255) wgt = 0.f;
                int yc = min(max(yi, 0), 255), xc = min(max(xi, 0), 255);
                t23.z = __int_as_float((base + (yc << 8) + xc) << 7); t23.w = wgt;
            }
            ((float4*)&taps[px][j][0])[0] = t01;
            ((float4*)&taps[px][j][0])[1] = t23;
        }
    }
    // F: scalar gather (R14 canonical form); lane = channel; ushort loads
    {
        int g4 = lane >> 4;
        const char* xgb = (const char*)xg;
        unsigned lane2 = (unsigned)(lane << 1);
        #pragma unroll
        for (int p = 0; p < 4; ++p) {
            float acc = 0.f;
            const float4* tp = (const float4*)&taps[pw + p][g4 * 9][0];
            #pragma unroll
            for (int k = 0; k < 9; ++k) {
                float4 d0 = tp[2 * k], d1 = tp[2 * k + 1];
                acc = fmaf(d0.y, bf2f(*(const unsigned short*)(xgb + ((unsigned)__float_as_int(d0.x) + lane2))), acc);
                acc = fmaf(d0.w, bf2f(*(const unsigned short*)(xgb + ((unsigned)__float_as_int(d0.z) + lane2))), acc);
                acc = fmaf(d1.y, bf2f(*(const unsigned short*)(xgb + ((unsigned)__float_as_int(d1.x) + lane2))), acc);
                acc = fmaf(d1.w, bf2f(*(const unsigned short*)(xgb + ((unsigned)__float_as_int(d1.z) + lane2))), acc);
            }
            accbf[pw + p][lane] = f2bf(acc);   // G
        }
    }
    __syncthreads();   // taps dead in all waves; accbf complete

    // H: out projection via MFMA. Wave w covers cols 16w..16w+15.
    {
        const unsigned short* arow = &accbf[lane & 15][(lane >> 4) << 3];
        short8v hf0 = *(const short8v*)arow;
        short8v hf1 = *(const short8v*)(arow + 32);
        int t = wave;
        int col = t * 16 + (lane & 15);
        float bo = bout[col];
        f32x4 acc = {bo, bo, bo, bo};
        short8v w0v = *(const short8v*)&WOpack[((t * 2 + 0) * 64 + lane) << 3];
        short8v w1v = *(const short8v*)&WOpack[((t * 2 + 1) * 64 + lane) << 3];
        acc = __builtin_amdgcn_mfma_f32_16x16x32_bf16(hf0, w0v, acc, 0, 0, 0);
        acc = __builtin_amdgcn_mfma_f32_16x16x32_bf16(hf1, w1v, acc, 0, 0, 0);
        int pxb = (lane >> 4) << 2;
        #pragma unroll
        for (int r = 0; r < 4; ++r)
            outs[pxb + r][col] = acc[r];
    }
    __syncthreads();

    int cq = tid >> 4, px = tid & 15;
    size_t rowb = ((size_t)(b * 64) << 16) + hw0 + px;
    #pragma unroll
    for (int rep = 0; rep < 4; ++rep) {
        int c = cq + rep * 16;
        out[rowb + ((size_t)c << 16)] = outs[px][c];
    }
}

extern "C" void kernel_launch(void* const* d_in, const int* in_sizes, int n_in,
                              void* d_out, int out_size, void* d_ws, size_t ws_size,
                              hipStream_t stream) {
    const float* x      = (const float*)d_in[0];
    const float* rw1    = (const float*)d_in[1];
    const float* rb1    = (const float*)d_in[2];
    const float* rw2    = (const float*)d_in[3];
    const float* rb2    = (const float*)d_in[4];
    const float* rw3    = (const float*)d_in[5];
    const float* rb3    = (const float*)d_in[6];
    const float* W_in   = (const float*)d_in[7];
    const float* b_in   = (const float*)d_in[8];
    const float* W_aop  = (const float*)d_in[9];
    const float* b_aop  = (const float*)d_in[10];
    const float* dw     = (const float*)d_in[11];
    const float* W_off  = (const float*)d_in[12];
    const float* b_off  = (const float*)d_in[13];
    const float* W_mask = (const float*)d_in[14];
    const float* b_mask = (const float*)d_in[15];
    const float* W_out  = (const float*)d_in[16];
    const float* b_out  = (const float*)d_in[17];
    float* out = (float*)d_out;

    // Large arrays FIRST; a2 rows 256B-aligned, xg (bf16) rows 128B-aligned.
    float* ws = (float*)d_ws;
    float* gray  = ws;                        // 131072
    float* h1    = gray + BHW_;               // 4194304
    float* h2    = h1 + (size_t)BHW_ * 32;    // 4194304
    float* a2    = h2 + (size_t)BHW_ * 32;    // 8388608  (256B-aligned)
    unsigned short* xgh = (unsigned short*)(a2 + (size_t)NPC);  // NPC bf16 = 16.8 MB
    float* bcomb = (float*)(xgh + (size_t)NPC);  // 128
    float* wT3   = bcomb + 128;               // 864
    unsigned short* WBpack = (unsigned short*)(wT3 + 864);   // 8192 bf16
    unsigned short* WOpack = WBpack + 8192;                  // 4096 bf16
    unsigned short* WB2    = WOpack + 4096;                  // 9216 bf16

    dim3 blk(256);

    k_mega<<<dim3(3073), blk, 0, stream>>>(x, gray, W_aop, b_aop, dw, a2,
                                           rw1, rb1, h1,
                                           W_off, b_off, W_mask, b_mask, W_out,
                                           rw2, rw3,
                                           WBpack, WOpack, WB2, bcomb, wT3);
    k_conv2m<<<dim3(BHW_ / 64), blk, 0, stream>>>(h1, WB2, rb2, h2);
    k_c3x<<<dim3(BHW_ / 256), blk, 0, stream>>>(x, gray, h2, wT3, rb3,
                                                W_in, b_in, xgh);
    k_dcn<<<dim3(BHW_ / 16), blk, 0, stream>>>(a2, xgh, WBpack, WOpack,
                                               bcomb, b_out, out);
}

// Round 17
// 156.378 us; speedup vs baseline: 1.2205x; 1.0317x over previous
//
#include <hip/hip_runtime.h>
#include <math.h>

#define H_ 256
#define W_ 256
#define HW_ 65536
#define BHW_ 131072   // B*H*W, B=2
#define NPC 8388608   // BHW_*64

typedef __attribute__((ext_vector_type(8))) short short8v;   // 8 bf16 (4 VGPRs)
typedef __attribute__((ext_vector_type(4))) float f32x4;

// gelu(x) = 0.5x(1+tanh(t)) == x * sigmoid(2t)
__device__ __forceinline__ float geluf(float x) {
    const float k2 = 2.f * 0.7978845608028654f;
    float t2 = k2 * (x + 0.044715f * x * x * x);
    return x / (1.f + __expf(-t2));
}
__device__ __forceinline__ float siluf(float x) {
    return x / (1.f + __expf(-x));
}
__device__ __forceinline__ unsigned short f2bf(float f) {   // RNE fp32->bf16
    unsigned u = __float_as_uint(f);
    u = (u + 0x7FFF + ((u >> 16) & 1)) >> 16;
    return (unsigned short)u;
}
__device__ __forceinline__ float bf2f(unsigned short s) {
    return __uint_as_float((unsigned)s << 16);
}

__device__ __forceinline__ float wcomb(const float* Woff, const float* Wmask, int c, int j) {
    return j < 72 ? Woff[c * 72 + j] : (j < 108 ? Wmask[c * 36 + (j - 72)] : 0.f);
}

// ---------- mega: poisson(0..511) | adw(512..2559) | conv1(2560..3071) | prep(3072) ----------
__global__ __launch_bounds__(256) void k_mega(const float* __restrict__ x,
        float* __restrict__ gray,
        const float* __restrict__ Wa, const float* __restrict__ ba,
        const float* __restrict__ dwW, unsigned short* __restrict__ a2,
        const float* __restrict__ rw1, const float* __restrict__ rb1,
        unsigned short* __restrict__ h1,
        const float* __restrict__ Woff, const float* __restrict__ boff,
        const float* __restrict__ Wmask, const float* __restrict__ bmask,
        const float* __restrict__ Wout, const float* __restrict__ rw2,
        const float* __restrict__ rw3,
        unsigned short* __restrict__ WBpack, unsigned short* __restrict__ WOpack,
        unsigned short* __restrict__ WB2,
        float* __restrict__ bcomb, float* __restrict__ wT3) {
    __shared__ float smem[3200];   // 12.8 KB
    int bid = blockIdx.x;
    int tid = threadIdx.x;

    if (bid < 512) {
        // ---- Poisson: div(regs) + 20 trapezoidal Jacobi iters; 16x16 tile, halo 20 ----
        float* u = smem;            // 56*57 = 3192 floats
        int b = bid >> 8, t = bid & 255;
        int qy = t >> 4, qx = t & 15;
        int y0i = qy << 4, x0i = qx << 4;
        int ys = max(y0i - 20, 0), ye = min(y0i + 35, 255);
        int xs = max(x0i - 20, 0), xe = min(x0i + 35, 255);
        int Ht = ye - ys + 1, Wt = xe - xs + 1;   // <= 56
        int ty = tid >> 5, tx = tid & 31;   // 8 x 32
        const float* x5 = x + ((size_t)(b * 9 + 5) << 16);
        const float* x6 = x + ((size_t)(b * 9 + 6) << 16);

        float dvr[7][2];
        #pragma unroll
        for (int i = 0; i < 7; ++i) {
            int yy = ty + i * 8;
            #pragma unroll
            for (int j = 0; j < 2; ++j) {
                int xx = tx + j * 32;
                if (yy < Ht && xx < Wt) {
                    int gy = ys + yy, gx = xs + xx;
                    int i00 = (gy << 8) + gx;
                    float v5 = x5[i00], v6 = x6[i00];
                    float d = -0.5f * (v5 + v6) + 0.5f * (v5 - v6);
                    if (gx > 0) d += 0.5f * (x5[i00 - 1] + x6[i00 - 1]);
                    if (gy > 0) d -= 0.5f * (x5[i00 - 256] - x6[i00 - 256]);
                    dvr[i][j] = d;
                    u[yy * 57 + xx] = 0.f;
                }
            }
        }
        __syncthreads();

        float nv[7][2];
        for (int it = 0; it < 20; ++it) {
            int r = 19 - it;
            int by0 = max(y0i - r, 0), by1 = min(y0i + 15 + r, 255);
            int bx0 = max(x0i - r, 0), bx1 = min(x0i + 15 + r, 255);
            #pragma unroll
            for (int i = 0; i < 7; ++i) {
                int yy = ty + i * 8;
                int gy = ys + yy;
                #pragma unroll
                for (int j = 0; j < 2; ++j) {
                    int xx = tx + j * 32;
                    int gx = xs + xx;
                    if (gy >= by0 && gy <= by1 && gx >= bx0 && gx <= bx1) {
                        int ym = (gy > 0 ? gy - 1 : 0) - ys;
                        int yp = (gy < 255 ? gy + 1 : 255) - ys;
                        int xm = (gx > 0 ? gx - 1 : 0) - xs;
                        int xp = (gx < 255 ? gx + 1 : 255) - xs;
                        nv[i][j] = (u[ym * 57 + xx] + u[yp * 57 + xx] +
                                    u[yy * 57 + xm] + u[yy * 57 + xp] - dvr[i][j]) * 0.25f;
                    }
                }
            }
            __syncthreads();
            #pragma unroll
            for (int i = 0; i < 7; ++i) {
                int yy = ty + i * 8;
                int gy = ys + yy;
                #pragma unroll
                for (int j = 0; j < 2; ++j) {
                    int xx = tx + j * 32;
                    int gx = xs + xx;
                    if (gy >= by0 && gy <= by1 && gx >= bx0 && gx <= bx1)
                        u[yy * 57 + xx] = nv[i][j];
                }
            }
            __syncthreads();
        }

        int oy = tid >> 4, ox = tid & 15;
        int gy = y0i + oy, gx = x0i + ox;
        gray[((size_t)b << 16) + (gy << 8) + gx] = u[(gy - ys) * 57 + (gx - xs)];

    } else if (bid < 2560) {
        // ---- fused aproj + depthwise + gelu: tile 8x8, halo 1; 'at' in bf16 ----
        unsigned short (*at)[64] = (unsigned short (*)[64])smem;   // 12.8 KB
        int abid = bid - 512;
        int b = abid >> 10, tb = abid & 1023;
        int ty0 = (tb >> 5) << 3, tx0 = (tb & 31) << 3;
        const float* g0p = x + ((size_t)(b * 9 + 7) << 16);
        const float* g1p = x + ((size_t)(b * 9 + 8) << 16);
        const float* g2p = x + ((size_t)(b * 9 + 5) << 16);
        const float* g3p = x + ((size_t)(b * 9 + 6) << 16);
        int c = tid & 63;
        float w0 = Wa[c], w1 = Wa[64 + c], w2 = Wa[128 + c], w3 = Wa[192 + c];
        float bb = ba[c];
        #pragma unroll
        for (int rep = 0; rep < 25; ++rep) {
            int pos = rep * 4 + (tid >> 6);
            int py = pos / 10, pxx = pos - py * 10;
            int gy = ty0 - 1 + py, gx = tx0 - 1 + pxx;
            float v = 0.f;
            if ((unsigned)gy < 256u && (unsigned)gx < 256u) {
                int ii = (gy << 8) + gx;
                float tv = bb + g0p[ii] * w0 + g1p[ii] * w1 + g2p[ii] * w2 + g3p[ii] * w3;
                v = geluf(tv);
            }
            at[pos][c] = f2bf(v);
        }
        __syncthreads();
        float dwr[9];
        #pragma unroll
        for (int k = 0; k < 9; ++k) dwr[k] = dwW[k * 64 + c];
        int pgrp = tid >> 6;
        #pragma unroll
        for (int i = 0; i < 16; ++i) {
            int pl = pgrp * 16 + i;
            int pyl = pl >> 3, pxl = pl & 7;
            float s = 0.f;
            #pragma unroll
            for (int kh = 0; kh < 3; ++kh)
                #pragma unroll
                for (int kw = 0; kw < 3; ++kw)
                    s += bf2f(at[(pyl + kh) * 10 + (pxl + kw)][c]) * dwr[kh * 3 + kw];
            int gy = ty0 + pyl, gx = tx0 + pxl;
            a2[(((size_t)(b << 16) + (gy << 8) + gx) << 6) + c] = f2bf(geluf(s));
        }

    } else if (bid < 3072) {
        // ---- conv1: 7 -> 32, silu -> bf16; LDS-transposed weights ----
        float* wsT = smem;   // 2016 floats
        for (int j = tid; j < 2016; j += 256) {
            int wb = j >> 5, o = j & 31;
            wsT[j] = rw1[o * 63 + wb];
        }
        __syncthreads();
        int cbid = bid - 2560;
        int wid = (cbid * 256 + tid) >> 6;
        int lane = tid & 63;
        int pix0 = wid << 6;
        int b = pix0 >> 16, hw0 = pix0 & 65535;
        int h = hw0 >> 8, w0 = hw0 & 255;
        float acc[32];
        #pragma unroll
        for (int o = 0; o < 32; ++o) acc[o] = rb1[o];
        const float* inb = x + ((size_t)(b * 9) << 16);
        #pragma unroll
        for (int kh = 0; kh < 3; ++kh) {
            int y = h + kh - 1;
            if ((unsigned)y >= 256u) continue;
            #pragma unroll
            for (int kw = 0; kw < 3; ++kw) {
                int xx = w0 + lane + kw - 1;
                bool valid = (unsigned)xx < 256u;
                int xc = min(max(xx, 0), 255);
                const float* p0 = inb + (y << 8) + xc;
                #pragma unroll
                for (int ci = 0; ci < 7; ++ci) {
                    float v = p0[ci << 16];
                    v = valid ? v : 0.f;
                    const float* wr = &wsT[(ci * 9 + kh * 3 + kw) * 32];
                    #pragma unroll
                    for (int o = 0; o < 32; ++o) acc[o] = fmaf(v, wr[o], acc[o]);
                }
            }
        }
        #pragma unroll
        for (int o = 0; o < 32; ++o)
            h1[((size_t)(b * 32 + o) << 16) + hw0 + lane] = f2bf(siluf(acc[o]));

    } else {
        // ---- prep: bf16 MFMA weight packs + bcomb + conv3 weight transpose ----
        for (int idx = tid; idx < 8192; idx += 256) {
            int j = idx & 7, l = (idx >> 3) & 63, s = (idx >> 9) & 1, t = idx >> 10;
            int c = s * 32 + ((l >> 4) << 3) + j;
            int col = t * 16 + (l & 15);
            WBpack[idx] = f2bf(wcomb(Woff, Wmask, c, col));
        }
        for (int idx = tid; idx < 4096; idx += 256) {
            int j = idx & 7, l = (idx >> 3) & 63, s = (idx >> 9) & 1, t = (idx >> 10) & 3;
            int c = s * 32 + ((l >> 4) << 3) + j;
            int col = t * 16 + (l & 15);
            WOpack[idx] = f2bf(Wout[c * 64 + col]);
        }
        for (int idx = tid; idx < 9216; idx += 256) {
            int j = idx & 7, l = (idx >> 3) & 63, t = (idx >> 9) & 1, kk = idx >> 10;
            int o = t * 16 + (l & 15);
            int ci = ((l >> 4) << 3) + j;
            WB2[idx] = f2bf(rw2[o * 288 + ci * 9 + kk]);
        }
        if (tid < 128) bcomb[tid] = tid < 72 ? boff[tid] : (tid < 108 ? bmask[tid - 72] : 0.f);
        for (int j = tid; j < 288 * 3; j += 256) {
            int jj = j / 3, o = j - jj * 3;
            wT3[j] = rw3[o * 288 + jj];
        }
    }
}

// ---------- conv2 via MFMA: bf16 h1 in -> bf16 h2 out; no per-element converts ----------
__global__ __launch_bounds__(256) void k_conv2m(const unsigned short* __restrict__ h1,
        const unsigned short* __restrict__ WB2, const float* __restrict__ bias,
        unsigned short* __restrict__ h2) {
    int tid = threadIdx.x;
    int wave = tid >> 6, lane = tid & 63;
    int pix0 = (blockIdx.x << 6) + (wave << 4);   // 16-px strip, single row
    int b = pix0 >> 16, hw0 = pix0 & 65535;
    int h = hw0 >> 8, w0 = hw0 & 255;
    int px = lane & 15, kg = lane >> 4;
    const unsigned short* inb = h1 + ((size_t)(b * 32) << 16);

    short8v af[9][2];
    #pragma unroll
    for (int kk = 0; kk < 9; ++kk) {
        af[kk][0] = *(const short8v*)&WB2[kk * 1024 + (lane << 3)];
        af[kk][1] = *(const short8v*)&WB2[kk * 1024 + 512 + (lane << 3)];
    }

    f32x4 acc0 = {0.f, 0.f, 0.f, 0.f};
    f32x4 acc1 = {0.f, 0.f, 0.f, 0.f};
    #pragma unroll
    for (int kh = 0; kh < 3; ++kh) {
        int y = h + kh - 1;
        if ((unsigned)y >= 256u) continue;     // wave-uniform zero-pad skip
        #pragma unroll
        for (int kw = 0; kw < 3; ++kw) {
            int xx = w0 + px + kw - 1;
            bool valid = (unsigned)xx < 256u;
            int xc = min(max(xx, 0), 255);
            const unsigned short* p0 = inb + (y << 8) + xc + ((size_t)kg << 19);
            short8v bfv;
            #pragma unroll
            for (int j = 0; j < 8; ++j) {
                unsigned short v = p0[(size_t)j << 16];
                bfv[j] = valid ? (short)v : (short)0;
            }
            int kk = kh * 3 + kw;
            acc0 = __builtin_amdgcn_mfma_f32_16x16x32_bf16(af[kk][0], bfv, acc0, 0, 0, 0);
            acc1 = __builtin_amdgcn_mfma_f32_16x16x32_bf16(af[kk][1], bfv, acc1, 0, 0, 0);
        }
    }
    size_t outb = ((size_t)(b * 32) << 16) + (size_t)(hw0 + px);
    #pragma unroll
    for (int r = 0; r < 4; ++r) {
        int o = (kg << 2) + r;
        h2[outb + ((size_t)o << 16)] = f2bf(siluf(acc0[r] + bias[o]));
        h2[outb + ((size_t)(o + 16) << 16)] = f2bf(siluf(acc1[r] + bias[o + 16]));
    }
}

// ---------- fused conv3 + xproj: bf16 h2 in, bf16 xg out ----------
__global__ __launch_bounds__(256) void k_c3x(const float* __restrict__ x,
        const float* __restrict__ gray, const unsigned short* __restrict__ h2,
        const float* __restrict__ wT3, const float* __restrict__ rb3,
        const float* __restrict__ Wi, const float* __restrict__ bi,
        unsigned short* __restrict__ xg) {
    __shared__ float st[7][256];
    int tid = threadIdx.x;
    int pixbase = blockIdx.x << 8;
    int pix = pixbase + tid;
    int b = pix >> 16, hw = pix & 65535;
    int h = hw >> 8, w = hw & 255;

    float a0 = rb3[0], a1 = rb3[1], a2v = rb3[2];
    const unsigned short* inb = h2 + ((size_t)(b * 32) << 16);
    #pragma unroll
    for (int kh = 0; kh < 3; ++kh) {
        int y = h + kh - 1;
        if ((unsigned)y >= 256u) continue;
        #pragma unroll
        for (int kw = 0; kw < 3; ++kw) {
            int xx = w + kw - 1;
            bool valid = (unsigned)xx < 256u;
            int xc = min(max(xx, 0), 255);
            const unsigned short* p0 = inb + (y << 8) + xc;
            #pragma unroll 8
            for (int ci = 0; ci < 32; ++ci) {
                float v = bf2f(p0[ci << 16]);
                v = valid ? v : 0.f;
                const float* wr = wT3 + (ci * 9 + kh * 3 + kw) * 3;
                a0 = fmaf(v, wr[0], a0);
                a1 = fmaf(v, wr[1], a1);
                a2v = fmaf(v, wr[2], a2v);
            }
        }
    }
    st[0][tid] = x[((size_t)(b * 9 + 0) << 16) + hw];
    st[1][tid] = x[((size_t)(b * 9 + 1) << 16) + hw];
    st[2][tid] = x[((size_t)(b * 9 + 2) << 16) + hw];
    st[3][tid] = gray[pix];
    st[4][tid] = a0;
    st[5][tid] = a1;
    st[6][tid] = a2v;
    __syncthreads();

    int c = tid & 63, sub = tid >> 6;
    float w0 = Wi[c], w1 = Wi[64 + c], w2 = Wi[128 + c], w3 = Wi[192 + c];
    float w4 = Wi[256 + c], w5 = Wi[320 + c], w6 = Wi[384 + c];
    float bb = bi[c];
    #pragma unroll 4
    for (int rep = 0; rep < 64; ++rep) {
        int pl = rep * 4 + sub;
        float v = bb + st[0][pl] * w0 + st[1][pl] * w1 + st[2][pl] * w2
                + st[3][pl] * w3 + st[4][pl] * w4 + st[5][pl] * w5 + st[6][pl] * w6;
        xg[(((size_t)(pixbase + pl)) << 6) + c] = f2bf(v);
    }
}

// ---------- DCNv3 core v9: MFMA projections + scalar gather over bf16 xg; bf16 a2 ----------
__global__ __launch_bounds__(256, 4) void k_dcn(
        const unsigned short* __restrict__ a2, const unsigned short* __restrict__ xg,
        const unsigned short* __restrict__ WBpack,
        const unsigned short* __restrict__ WOpack,
        const float* __restrict__ bcomb, const float* __restrict__ bout,
        float* __restrict__ out) {
    __shared__ __attribute__((aligned(16))) unsigned short a2bf[16][72];  // bf16, padded
    __shared__ __attribute__((aligned(16))) unsigned short accbf[16][72];
    __shared__ __attribute__((aligned(16))) float offs[16][72];
    __shared__ float pms[16][36];
    __shared__ float invs[16][4];
    __shared__ __attribute__((aligned(16))) float taps[16][36][8]; // then outs[16][65]
    float (*outs)[65] = (float (*)[65])&taps[0][0][0];

    int tid = threadIdx.x;
    int wave = tid >> 6, lane = tid & 63;
    int pixbase = blockIdx.x << 4;
    int b = pixbase >> 16, hw0 = pixbase & 65535;
    int h = hw0 >> 8, w0 = hw0 & 255;
    int pw = wave << 2;

    #pragma unroll
    for (int p = 0; p < 4; ++p)
        a2bf[pw + p][lane] = a2[((size_t)(pixbase + pw + p) << 6) + lane];
    __syncthreads();

    // B: off(72)+mask(36) projection via MFMA. Wave w covers cols 32w..32w+31.
    {
        const unsigned short* arow = &a2bf[lane & 15][(lane >> 4) << 3];
        short8v af0 = *(const short8v*)arow;
        short8v af1 = *(const short8v*)(arow + 32);
        #pragma unroll
        for (int t2 = 0; t2 < 2; ++t2) {
            int t = 2 * wave + t2;
            int col = t * 16 + (lane & 15);
            float bc = bcomb[col];
            f32x4 acc = {bc, bc, bc, bc};
            short8v b0 = *(const short8v*)&WBpack[((t * 2 + 0) * 64 + lane) << 3];
            short8v b1 = *(const short8v*)&WBpack[((t * 2 + 1) * 64 + lane) << 3];
            acc = __builtin_amdgcn_mfma_f32_16x16x32_bf16(af0, b0, acc, 0, 0, 0);
            acc = __builtin_amdgcn_mfma_f32_16x16x32_bf16(af1, b1, acc, 0, 0, 0);
            int pxb = (lane >> 4) << 2;
            #pragma unroll
            for (int r = 0; r < 4; ++r) {
                float v = acc[r];
                int px = pxb + r;
                if (col < 72) offs[px][col] = v;
                else if (col < 108) pms[px][col - 72] = __expf(v);   // shift-free softmax
            }
        }
    }
    __syncthreads();

    if (lane < 16) {
        int p = lane >> 2, g = lane & 3;
        const float* m = &pms[pw + p][g * 9];
        float s = m[0]+m[1]+m[2]+m[3]+m[4]+m[5]+m[6]+m[7]+m[8];
        invs[pw + p][g] = 1.f / s;
    }
    // E: tap descriptors (BYTE offsets = spatial<<7, bf16 rows), 144 jobs
    #pragma unroll
    for (int rep = 0; rep < 3; ++rep) {
        int idx = rep * 64 + lane;
        if (idx < 144) {
            int p = idx / 36, j = idx - p * 36;
            int px = pw + p;
            int g = j / 9, k = j - g * 9;
            float2 oxy = ((const float2*)&offs[px][0])[j];
            float pm = pms[px][j] * invs[px][g];
            float ly = (float)(h + k / 3 - 1) + oxy.x;
            float lx = (float)(w0 + px + (k % 3) - 1) + oxy.y;
            float y0f = floorf(ly), x0f = floorf(lx);
            float wy = ly - y0f, wx = lx - x0f;
            int iy0 = (int)y0f, ix0 = (int)x0f;
            int base = b << 16;
            float4 t01, t23;
            {
                int yi = iy0, xi = ix0;
                float wgt = (1.f - wy) * (1.f - wx) * pm;
                if (yi < 0 || yi > 255 || xi < 0 || xi > 255) wgt = 0.f;
                int yc = min(max(yi, 0), 255), xc = min(max(xi, 0), 255);
                t01.x = __int_as_float((base + (yc << 8) + xc) << 7); t01.y = wgt;
            }
            {
                int yi = iy0, xi = ix0 + 1;
                float wgt = (1.f - wy) * wx * pm;
                if (yi < 0 || yi > 255 || xi < 0 || xi > 255) wgt = 0.f;
                int yc = min(max(yi, 0), 255), xc = min(max(xi, 0), 255);
                t01.z = __int_as_float((base + (yc << 8) + xc) << 7); t01.w = wgt;
            }
            {
                int yi = iy0 + 1, xi = ix0;
                float wgt = wy * (1.f - wx) * pm;
                if (yi < 0 || yi > 255 || xi < 0 || xi > 255) wgt = 0.f;
                int yc = min(max(yi, 0), 255), xc = min(max(xi, 0), 255);
                t23.x = __int_as_float((base + (yc << 8) + xc) << 7); t23.y = wgt;
            }
            {
                int yi = iy0 + 1, xi = ix0 + 1;
                float wgt = wy * wx * pm;
                if (yi < 0 || yi > 255 || xi < 0 || xi > 255) wgt = 0.f;
                int yc = min(max(yi, 0), 255), xc = min(max(xi, 0), 255);
                t23.z = __int_as_float((base + (yc << 8) + xc) << 7); t23.w = wgt;
            }
            ((float4*)&taps[px][j][0])[0] = t01;
            ((float4*)&taps[px][j][0])[1] = t23;
        }
    }
    // F: scalar gather; lane = channel; ushort loads
    {
        int g4 = lane >> 4;
        const char* xgb = (const char*)xg;
        unsigned lane2 = (unsigned)(lane << 1);
        #pragma unroll
        for (int p = 0; p < 4; ++p) {
            float acc = 0.f;
            const float4* tp = (const float4*)&taps[pw + p][g4 * 9][0];
            #pragma unroll
            for (int k = 0; k < 9; ++k) {
                float4 d0 = tp[2 * k], d1 = tp[2 * k + 1];
                acc = fmaf(d0.y, bf2f(*(const unsigned short*)(xgb + ((unsigned)__float_as_int(d0.x) + lane2))), acc);
                acc = fmaf(d0.w, bf2f(*(const unsigned short*)(xgb + ((unsigned)__float_as_int(d0.z) + lane2))), acc);
                acc = fmaf(d1.y, bf2f(*(const unsigned short*)(xgb + ((unsigned)__float_as_int(d1.x) + lane2))), acc);
                acc = fmaf(d1.w, bf2f(*(const unsigned short*)(xgb + ((unsigned)__float_as_int(d1.z) + lane2))), acc);
            }
            accbf[pw + p][lane] = f2bf(acc);   // G
        }
    }
    __syncthreads();   // taps dead in all waves; accbf complete

    // H: out projection via MFMA. Wave w covers cols 16w..16w+15.
    {
        const unsigned short* arow = &accbf[lane & 15][(lane >> 4) << 3];
        short8v hf0 = *(const short8v*)arow;
        short8v hf1 = *(const short8v*)(arow + 32);
        int t = wave;
        int col = t * 16 + (lane & 15);
        float bo = bout[col];
        f32x4 acc = {bo, bo, bo, bo};
        short8v w0v = *(const short8v*)&WOpack[((t * 2 + 0) * 64 + lane) << 3];
        short8v w1v = *(const short8v*)&WOpack[((t * 2 + 1) * 64 + lane) << 3];
        acc = __builtin_amdgcn_mfma_f32_16x16x32_bf16(hf0, w0v, acc, 0, 0, 0);
        acc = __builtin_amdgcn_mfma_f32_16x16x32_bf16(hf1, w1v, acc, 0, 0, 0);
        int pxb = (lane >> 4) << 2;
        #pragma unroll
        for (int r = 0; r < 4; ++r)
            outs[pxb + r][col] = acc[r];
    }
    __syncthreads();

    int cq = tid >> 4, px = tid & 15;
    size_t rowb = ((size_t)(b * 64) << 16) + hw0 + px;
    #pragma unroll
    for (int rep = 0; rep < 4; ++rep) {
        int c = cq + rep * 16;
        out[rowb + ((size_t)c << 16)] = outs[px][c];
    }
}

extern "C" void kernel_launch(void* const* d_in, const int* in_sizes, int n_in,
                              void* d_out, int out_size, void* d_ws, size_t ws_size,
                              hipStream_t stream) {
    const float* x      = (const float*)d_in[0];
    const float* rw1    = (const float*)d_in[1];
    const float* rb1    = (const float*)d_in[2];
    const float* rw2    = (const float*)d_in[3];
    const float* rb2    = (const float*)d_in[4];
    const float* rw3    = (const float*)d_in[5];
    const float* rb3    = (const float*)d_in[6];
    const float* W_in   = (const float*)d_in[7];
    const float* b_in   = (const float*)d_in[8];
    const float* W_aop  = (const float*)d_in[9];
    const float* b_aop  = (const float*)d_in[10];
    const float* dw     = (const float*)d_in[11];
    const float* W_off  = (const float*)d_in[12];
    const float* b_off  = (const float*)d_in[13];
    const float* W_mask = (const float*)d_in[14];
    const float* b_mask = (const float*)d_in[15];
    const float* W_out  = (const float*)d_in[16];
    const float* b_out  = (const float*)d_in[17];
    float* out = (float*)d_out;

    // Large arrays FIRST; all bf16 arrays keep 128B-aligned pixel rows.
    float* ws = (float*)d_ws;
    float* gray  = ws;                                   // 131072 f32
    unsigned short* h1  = (unsigned short*)(gray + BHW_);      // BHW_*32 bf16 = 8.4 MB
    unsigned short* h2  = h1 + (size_t)BHW_ * 32;              // 8.4 MB
    unsigned short* a2  = h2 + (size_t)BHW_ * 32;              // NPC bf16 = 16.8 MB
    unsigned short* xgh = a2 + (size_t)NPC;                    // 16.8 MB
    float* bcomb = (float*)(xgh + (size_t)NPC);          // 128
    float* wT3   = bcomb + 128;                          // 864
    unsigned short* WBpack = (unsigned short*)(wT3 + 864);   // 8192 bf16
    unsigned short* WOpack = WBpack + 8192;                  // 4096 bf16
    unsigned short* WB2    = WOpack + 4096;                  // 9216 bf16

    dim3 blk(256);

    k_mega<<<dim3(3073), blk, 0, stream>>>(x, gray, W_aop, b_aop, dw, a2,
                                           rw1, rb1, h1,
                                           W_off, b_off, W_mask, b_mask, W_out,
                                           rw2, rw3,
                                           WBpack, WOpack, WB2, bcomb, wT3);
    k_conv2m<<<dim3(BHW_ / 64), blk, 0, stream>>>(h1, WB2, rb2, h2);
    k_c3x<<<dim3(BHW_ / 256), blk, 0, stream>>>(x, gray, h2, wT3, rb3,
                                                W_in, b_in, xgh);
    k_dcn<<<dim3(BHW_ / 16), blk, 0, stream>>>(a2, xgh, WBpack, WOpack,
                                               bcomb, b_out, out);
}